// Round 2
// baseline (177.184 us; speedup 1.0000x reference)
//
#include <hip/hip_runtime.h>
#include <hip/hip_bf16.h>

// y_i = x_i^T Q x_i + b^T x_i + c ; N=16384, D=1024, fp32.
// Round 6: TRUE occupancy fix + traffic cut. R5 post-mortem: VGPR 88 +
// AGPR 64 = 152 UNIFIED regs -> 129-256 band -> still 8 waves/CU (same as
// R4: both ~77us, Occ ~20%, neutral). This round: <=128 unified regs AND
// grid 1024:
//   - 256-thr blocks (4 waves x 32 rows = 128 rows/block)
//   - KH=128 (K-split 8) -> A frags = 32 AGPR
//   - NO column split -> x read ONCE for A (67 MB, was 134)
//   - grid = 128 rblk x 8 kq = 1024 = 4 blocks/CU; launch_bounds(256,4)
//   - Q staged fp32 via global_load_lds (zero staging VGPRs/VALU);
//     global source XOR-pre-swizzled (byte ^ ((row&7)<<4)) since the LDS
//     dest must stay linear (m104) -> B-frag ds_read_b128 spreads all 32
//     banks; fp32->bf16 convert at frag read (f2b, compiler packs).
//   - kq = blockIdx&7 aligns with XCD round-robin: each XCD's L2 holds
//     one 0.5 MB Q-eighth.
// Est ~60 VGPR + 32 AGPR = ~92 unified -> 16 waves/CU, no spill risk.

#define DD 1024
#define KH 128           // K per block (K-split 8)
#define KSTEP 4          // KH/32 MFMA k-steps per round
#define NT 64            // rounds of 16 Q-rows (output cols) each
#define ROWB 512         // bytes per LDS row (KH * 4)
#define TILEB 8192       // bytes per LDS buffer (16 * ROWB)

typedef short v8s __attribute__((ext_vector_type(8)));
typedef float v4f __attribute__((ext_vector_type(4)));

__device__ __forceinline__ short f2b(float f) {
    union { __hip_bfloat16 h; short s; } u;
    u.h = __float2bfloat16(f);
    return u.s;
}

__global__ __launch_bounds__(256, 4)
void quad_kernel(const float* __restrict__ x, const float* __restrict__ Q,
                 const float* __restrict__ bvec, const float* __restrict__ cptr,
                 float* __restrict__ y)
{
    // 2 x 8 KB fp32 staging buffers; content is XOR-swizzled per row,
    // layout is LINEAR (global_load_lds requirement).
    __shared__ __align__(1024) float lq[2][16 * KH];

    const int tid  = threadIdx.x;
    const int lane = tid & 63;
    const int wave = tid >> 6;       // 0..3
    const int quad = lane >> 4;
    const int l15  = lane & 15;

    const int kq   = blockIdx.x & 7;     // K eighth 0..7
    const int rblk = blockIdx.x >> 3;    // 0..127
    const int row_base = rblk * 128 + wave * 32;
    const int kofs = kq * KH;

    // ---- DMA lane map: 2 instrs/wave; instr j writes LDS rows r0=wave*4+2j,
    // r0+1 (1 KB linear). lane l -> row r0+(l>>5), row-byte ((l&31)*16)^((r&7)<<4).
    int grow[2], goff[2];
    #pragma unroll
    for (int j = 0; j < 2; ++j) {
        const int r = wave * 4 + j * 2 + (lane >> 5);
        grow[j] = r;
        goff[j] = ((lane & 31) * 16) ^ ((r & 7) << 4);
    }

    // issue tile-0 DMA first so it overlaps the A-load phase
    #pragma unroll
    for (int j = 0; j < 2; ++j) {
        const char* gp = (const char*)(Q + (size_t)grow[j] * DD + kofs) + goff[j];
        __builtin_amdgcn_global_load_lds(
            (const __attribute__((address_space(1))) unsigned int*)gp,
            (__attribute__((address_space(3))) unsigned int*)
                ((char*)&lq[0][0] + (wave * 4 + j * 2) * ROWB),
            16, 0, 0);
    }

    // ---- Phase 1: A = x[32 rows][kofs..kofs+128) bf16 frags in AGPRs ----
    // A layout (16x16x32): m = lane&15, k = quad*8 + jj (8 contiguous bf16)
    v8s a[2][KSTEP];
    #pragma unroll
    for (int g = 0; g < 2; ++g) {
        const float* xr = x + (size_t)(row_base + g * 16 + l15) * DD + kofs + quad * 8;
        #pragma unroll
        for (int s = 0; s < KSTEP; ++s) {
            const float4 f0 = *(const float4*)(xr + s * 32);
            const float4 f1 = *(const float4*)(xr + s * 32 + 4);
            v8s t;
            t[0]=f2b(f0.x); t[1]=f2b(f0.y); t[2]=f2b(f0.z); t[3]=f2b(f0.w);
            t[4]=f2b(f1.x); t[5]=f2b(f1.y); t[6]=f2b(f1.z); t[7]=f2b(f1.w);
            a[g][s] = t;
            asm volatile("" : "+a"(a[g][s]));   // force AGPR residency
        }
    }

    // B-frag LDS read bases: row l15, byte (quad*32 + half*16 + s*128) ^ xorc.
    // XOR only touches bits 4-6, so s*128 folds into ds_read imm offsets.
    const int xorc = (l15 & 7) << 4;
    const int lp0 = l15 * ROWB + ((quad * 32     ) ^ xorc);
    const int lp1 = l15 * ROWB + ((quad * 32 + 16) ^ xorc);
    const char* lbase = (const char*)&lq[0][0];

    float acc[2][4];
    #pragma unroll
    for (int g = 0; g < 2; ++g)
        #pragma unroll
        for (int r = 0; r < 4; ++r) acc[g][r] = 0.f;

    for (int t = 0; t < NT; ++t) {
        // implicit s_waitcnt vmcnt(0) before s_barrier: buf[t&1] DMA done,
        // and everyone finished reading buf[(t+1)&1] in round t-1.
        __syncthreads();

        // issue next tile's DMA immediately; ~1 round of compute hides it
        if (t + 1 < NT) {
            #pragma unroll
            for (int j = 0; j < 2; ++j) {
                const char* gp = (const char*)(Q + (size_t)((t + 1) * 16 + grow[j]) * DD + kofs) + goff[j];
                __builtin_amdgcn_global_load_lds(
                    (const __attribute__((address_space(1))) unsigned int*)gp,
                    (__attribute__((address_space(3))) unsigned int*)
                        ((char*)&lq[(t + 1) & 1][0] + (wave * 4 + j * 2) * ROWB),
                    16, 0, 0);
            }
        }

        // fused-dot operands for this round's 16 columns
        const int n0 = t * 16 + l15;
        const float bn = (kq == 0) ? bvec[n0] : 0.f;
        float xv[2][4];
        {
            const float* xc = x + (size_t)(row_base + quad * 4) * DD + n0;
            #pragma unroll
            for (int g = 0; g < 2; ++g)
                #pragma unroll
                for (int r = 0; r < 4; ++r)
                    xv[g][r] = xc[(size_t)(g * 16 + r) * DD];
        }

        // MFMA: read fp32 B-frags (swizzled), convert to bf16, 2 row-chains
        const char* lb = lbase + (t & 1) * TILEB;
        v4f cf[2];
        cf[0] = (v4f){0.f, 0.f, 0.f, 0.f};
        cf[1] = (v4f){0.f, 0.f, 0.f, 0.f};
        #pragma unroll
        for (int s = 0; s < KSTEP; ++s) {
            const float4 q0 = *(const float4*)(lb + lp0 + s * 128);
            const float4 q1 = *(const float4*)(lb + lp1 + s * 128);
            v8s bf;
            bf[0]=f2b(q0.x); bf[1]=f2b(q0.y); bf[2]=f2b(q0.z); bf[3]=f2b(q0.w);
            bf[4]=f2b(q1.x); bf[5]=f2b(q1.y); bf[6]=f2b(q1.z); bf[7]=f2b(q1.w);
            cf[0] = __builtin_amdgcn_mfma_f32_16x16x32_bf16(a[0][s], bf, cf[0], 0, 0, 0);
            cf[1] = __builtin_amdgcn_mfma_f32_16x16x32_bf16(a[1][s], bf, cf[1], 0, 0, 0);
        }

        // fused dot: C layout col = lane&15, row = quad*4 + reg
        #pragma unroll
        for (int g = 0; g < 2; ++g)
            #pragma unroll
            for (int r = 0; r < 4; ++r)
                acc[g][r] += (cf[g][r] + bn) * xv[g][r];
    }

    // ---- reduce across the 16 lanes of each quad, atomic into y ----
    const float cc = (kq == 0) ? cptr[0] : 0.f;  // c added once per row
    #pragma unroll
    for (int g = 0; g < 2; ++g) {
        #pragma unroll
        for (int r = 0; r < 4; ++r) {
            float v = acc[g][r];
            v += __shfl_xor(v, 1); v += __shfl_xor(v, 2);
            v += __shfl_xor(v, 4); v += __shfl_xor(v, 8);
            if (l15 == 0)
                atomicAdd(&y[row_base + g * 16 + quad * 4 + r], v + cc);
        }
    }
}

extern "C" void kernel_launch(void* const* d_in, const int* in_sizes, int n_in,
                              void* d_out, int out_size, void* d_ws, size_t ws_size,
                              hipStream_t stream)
{
    const float* x = (const float*)d_in[0];
    const float* Q = (const float*)d_in[1];
    const float* b = (const float*)d_in[2];
    const float* c = (const float*)d_in[3];
    float* y = (float*)d_out;

    hipMemsetAsync(y, 0, (size_t)out_size * sizeof(float), stream);
    quad_kernel<<<dim3(1024), dim3(256), 0, stream>>>(x, Q, b, c, y);
}